// Round 2
// baseline (108.078 us; speedup 1.0000x reference)
//
#include <hip/hip_runtime.h>

typedef __attribute__((ext_vector_type(8))) __bf16 bf16x8;
typedef __attribute__((ext_vector_type(4))) float f32x4;

__device__ __forceinline__ unsigned short f2bf(float f) {
    unsigned int u = __builtin_bit_cast(unsigned int, f);
    u = (u + 0x7FFFu + ((u >> 16) & 1u)) >> 16;
    return (unsigned short)u;
}

// ---- K0a: transpose-cast identity half (ch 0..31) to channel-last bf16 ----
__global__ void __launch_bounds__(256) prep_x1(const float* __restrict__ x,
                                               unsigned short* __restrict__ x1b) {
    int bh = blockIdx.x;                  // b*64 + h
    __shared__ unsigned short lds[64][34];
    int t = threadIdx.x;
    int w = t & 63, c4 = t >> 6;
    const float* xp = x + (size_t)(bh >> 6) * 262144 + (size_t)(bh & 63) * 64;
#pragma unroll
    for (int co = 0; co < 8; ++co) {
        int c = co * 4 + c4;
        lds[w][c] = f2bf(xp[(size_t)c * 4096 + w]);
    }
    __syncthreads();
    int wq = t >> 2, c0 = (t & 3) * 8;
    uint4 v;
    unsigned short* pv = reinterpret_cast<unsigned short*>(&v);
#pragma unroll
    for (int j = 0; j < 8; ++j) pv[j] = lds[wq][c0 + j];
    *reinterpret_cast<uint4*>(x1b + ((size_t)bh * 64 + wq) * 32 + c0) = v;
}

// ---- K0b: copy identity half f32 -> out ch 0..31 ; init objective slots ----
__global__ void __launch_bounds__(256) prep_copy(const float* __restrict__ x,
                                                 const float* __restrict__ obj,
                                                 float* __restrict__ out) {
    unsigned tid = blockIdx.x * 256 + threadIdx.x;   // 1,048,576 float4 total
    unsigned b = tid >> 15, r = tid & 32767;
    size_t off = (size_t)b * 65536 + r;
    reinterpret_cast<float4*>(out)[off] = reinterpret_cast<const float4*>(x)[off];
    if (tid < 32) out[8388608 + tid] = obj[tid];
}

// ---- K0c: repack weights to [tap][o][i] bf16 ----
__global__ void __launch_bounds__(256) prep_w(const float* __restrict__ W1,
                                              const float* __restrict__ W2,
                                              unsigned short* __restrict__ Wt1,
                                              unsigned short* __restrict__ Wt2) {
    int tid = blockIdx.x * 256 + threadIdx.x;
    if (tid < 36864) {                       // W1: [128][32][9]
        int tt = tid % 9, rem = tid / 9;
        int i = rem & 31, o = rem >> 5;
        Wt1[(tt * 128 + o) * 32 + i] = f2bf(W1[tid]);
    }
    if (tid < 110592) {                      // W2: [96][128][9]
        int tt = tid % 9, rem = tid / 9;
        int i = rem & 127, o = rem >> 7;
        Wt2[(tt * 96 + o) * 128 + i] = f2bf(W2[tid]);
    }
}

// ---- K1: conv1 (32->128 ch) + bias + ReLU -> h bf16 channel-last ----
__global__ void __launch_bounds__(256) conv1_relu(const unsigned short* __restrict__ x1b,
                                                  const float* __restrict__ b1,
                                                  const unsigned short* __restrict__ Wt1,
                                                  unsigned short* __restrict__ hbuf) {
    const int LW = 40;                          // 32 ch + 8 pad (bank spread)
    __shared__ unsigned short sx[6 * 66 * LW];  // 31,680 B
    int wg = blockIdx.x;
    int b = wg >> 4, h0 = (wg & 15) << 2;       // TH = 4 rows
    int t = threadIdx.x;

    if (t < 48) {                               // zero halo cols 0 and 65
        int row = t >> 3, k = t & 7;
        int col = (k & 1) ? 65 : 0, c0 = (k >> 1) * 8;
        *reinterpret_cast<uint4*>(&sx[(row * 66 + col) * LW + c0]) = uint4{0, 0, 0, 0};
    }
#pragma unroll
    for (int j = 0; j < 6; ++j) {               // stage 6 rows x 64 w x 32 ch
        int idx = j * 256 + t;
        int row = idx >> 8, rem = idx & 255;
        int w = rem >> 2, c0 = (rem & 3) * 8;
        int gh = h0 - 1 + row;
        uint4 v = uint4{0, 0, 0, 0};
        if (gh >= 0 && gh < 64)
            v = *reinterpret_cast<const uint4*>(x1b + (((size_t)b * 64 + gh) * 64 + w) * 32 + c0);
        *reinterpret_cast<uint4*>(&sx[(row * 66 + (w + 1)) * LW + c0]) = v;
    }
    __syncthreads();

    int wid = t >> 6, lane = t & 63;
    int lrow = lane & 15, kgrp = lane >> 4;

    bf16x8 afr[2][9];                           // hoist weights: 2 M-tiles x 9 taps
#pragma unroll
    for (int m2 = 0; m2 < 2; ++m2) {
        int o = (wid * 2 + m2) * 16 + lrow;
#pragma unroll
        for (int tap = 0; tap < 9; ++tap)
            afr[m2][tap] = *reinterpret_cast<const bf16x8*>(
                Wt1 + (size_t)(tap * 128 + o) * 32 + kgrp * 8);
    }

    for (int nt = 0; nt < 16; ++nt) {
        int r = nt >> 2, ww = ((nt & 3) << 4) + lrow;
        f32x4 acc0 = {0.f, 0.f, 0.f, 0.f}, acc1 = {0.f, 0.f, 0.f, 0.f};
#pragma unroll
        for (int dh = 0; dh < 3; ++dh)
#pragma unroll
            for (int dw = 0; dw < 3; ++dw) {
                int tap = dh * 3 + dw;
                bf16x8 bfr = *reinterpret_cast<const bf16x8*>(
                    &sx[((r + dh) * 66 + ww + dw) * LW + kgrp * 8]);
                acc0 = __builtin_amdgcn_mfma_f32_16x16x32_bf16(afr[0][tap], bfr, acc0, 0, 0, 0);
                acc1 = __builtin_amdgcn_mfma_f32_16x16x32_bf16(afr[1][tap], bfr, acc1, 0, 0, 0);
            }
        int hh = h0 + r;
        size_t obase = (((size_t)b * 64 + hh) * 64 + ww) * 128;
#pragma unroll
        for (int m2 = 0; m2 < 2; ++m2) {
            f32x4 a = (m2 == 0) ? acc0 : acc1;
            int o0 = (wid * 2 + m2) * 16 + kgrp * 4;
            unsigned short r4[4];
#pragma unroll
            for (int j = 0; j < 4; ++j) {
                float v = a[j] + b1[o0 + j];
                r4[j] = f2bf(fmaxf(v, 0.f));
            }
            uint2 pk;
            pk.x = (unsigned)r4[0] | ((unsigned)r4[1] << 16);
            pk.y = (unsigned)r4[2] | ((unsigned)r4[3] << 16);
            *reinterpret_cast<uint2*>(hbuf + obase + o0) = pk;
        }
    }
}

// ---- K2: conv2 (128->96 ch) + bias -> params (LDS) -> spline -> out ----
__global__ void __launch_bounds__(256) conv2_spline(const unsigned short* __restrict__ hbuf,
                                                    const float* __restrict__ b2,
                                                    const unsigned short* __restrict__ Wt2,
                                                    const float* __restrict__ x,
                                                    float* __restrict__ out) {
    const int LW = 72;                         // 64-ch chunk + 8 pad
    __shared__ float smem[12800];              // 51,200 B: staging (bf16) then params [128][100] f32
    __shared__ float red[4];
    unsigned short* sx = reinterpret_cast<unsigned short*>(smem);
    int wg = blockIdx.x;
    int b = wg >> 5, h0 = (wg & 31) << 1;      // TH = 2 rows
    int t = threadIdx.x;
    int wid = t >> 6, lane = t & 63;
    int lrow = lane & 15, kgrp = lane >> 4;
    int ntb = (wid & 1) * 4;                   // wave's 4 N-tiles
    int mb = (wid >> 1) * 3;                   // wave's 3 M-tiles

    f32x4 acc[3][4];
#pragma unroll
    for (int i = 0; i < 3; ++i)
#pragma unroll
        for (int j = 0; j < 4; ++j) acc[i][j] = f32x4{0.f, 0.f, 0.f, 0.f};

    for (int kc2 = 0; kc2 < 2; ++kc2) {        // two 64-channel K chunks
        __syncthreads();
        if (t < 64) {                          // zero halo cols
            int row = t >> 4, k = t & 15;
            int col = (k & 1) ? 65 : 0, c0 = (k >> 1) * 8;
            *reinterpret_cast<uint4*>(&sx[(row * 66 + col) * LW + c0]) = uint4{0, 0, 0, 0};
        }
#pragma unroll
        for (int j = 0; j < 8; ++j) {          // stage 4 rows x 64 w x 64 ch
            int idx = j * 256 + t;
            int row = idx >> 9, rem = idx & 511;
            int w = rem >> 3, c0 = (rem & 7) * 8;
            int gh = h0 - 1 + row;
            uint4 v = uint4{0, 0, 0, 0};
            if (gh >= 0 && gh < 64)
                v = *reinterpret_cast<const uint4*>(
                    hbuf + (((size_t)b * 64 + gh) * 64 + w) * 128 + kc2 * 64 + c0);
            *reinterpret_cast<uint4*>(&sx[(row * 66 + (w + 1)) * LW + c0]) = v;
        }
        __syncthreads();

#pragma unroll
        for (int tap = 0; tap < 9; ++tap) {
            int dh = tap / 3, dw = tap % 3;
            bf16x8 bfr[4][2];
#pragma unroll
            for (int ni = 0; ni < 4; ++ni) {
                int nt = ntb + ni;
                int rr = nt >> 2, ww = ((nt & 3) << 4) + lrow;
#pragma unroll
                for (int kc = 0; kc < 2; ++kc)
                    bfr[ni][kc] = *reinterpret_cast<const bf16x8*>(
                        &sx[((rr + dh) * 66 + ww + dw) * LW + kc * 32 + kgrp * 8]);
            }
#pragma unroll
            for (int mi = 0; mi < 3; ++mi) {
                int o = (mb + mi) * 16 + lrow;
                const unsigned short* wp =
                    Wt2 + (size_t)(tap * 96 + o) * 128 + kc2 * 64 + kgrp * 8;
                bf16x8 a0 = *reinterpret_cast<const bf16x8*>(wp);
                bf16x8 a1 = *reinterpret_cast<const bf16x8*>(wp + 32);
#pragma unroll
                for (int ni = 0; ni < 4; ++ni) {
                    acc[mi][ni] = __builtin_amdgcn_mfma_f32_16x16x32_bf16(a0, bfr[ni][0], acc[mi][ni], 0, 0, 0);
                    acc[mi][ni] = __builtin_amdgcn_mfma_f32_16x16x32_bf16(a1, bfr[ni][1], acc[mi][ni], 0, 0, 0);
                }
            }
        }
    }
    __syncthreads();
    // params (+bias) -> LDS [p][100]
#pragma unroll
    for (int mi = 0; mi < 3; ++mi) {
        int o0 = (mb + mi) * 16 + kgrp * 4;
        float bb0 = b2[o0], bb1 = b2[o0 + 1], bb2 = b2[o0 + 2], bb3 = b2[o0 + 3];
#pragma unroll
        for (int ni = 0; ni < 4; ++ni) {
            int p = (ntb + ni) * 16 + lrow;
            f32x4 v = acc[mi][ni];
            v[0] += bb0; v[1] += bb1; v[2] += bb2; v[3] += bb3;
            *reinterpret_cast<f32x4*>(&smem[p * 100 + o0]) = v;
        }
    }
    __syncthreads();

    // fused softmax + linear spline + identity tails + logabsdet
    float lad_acc = 0.f;
#pragma unroll 4
    for (int it = 0; it < 16; ++it) {
        int idx = it * 256 + t;
        int c = idx >> 7, p = idx & 127;
        float u0 = smem[p * 100 + 3 * c];
        float u1 = smem[p * 100 + 3 * c + 1];
        float u2 = smem[p * 100 + 3 * c + 2];
        size_t gpos = (size_t)(b * 64 + 32 + c) * 4096 + (size_t)(h0 + (p >> 6)) * 64 + (p & 63);
        float xin = x[gpos];
        float mx = fmaxf(u0, fmaxf(u1, u2));
        float e0 = __expf(u0 - mx), e1 = __expf(u1 - mx), e2 = __expf(u2 - mx);
        float s = e0 + e1 + e2;
        float inv = 1.0f / s;
        float pos = fminf(fmaxf((xin + 1.f) * 0.5f, 0.f), 1.f) * 3.f;
        int bin = (int)pos; bin = bin > 2 ? 2 : bin;
        float alpha = pos - (float)bin;
        float eb = (bin == 0) ? e0 : ((bin == 1) ? e1 : e2);
        float cb = (bin == 0) ? 0.f : ((bin == 1) ? e0 : (e0 + e1));
        float pk = eb * inv;
        float outv = cb * inv + alpha * pk;
        outv = fminf(fmaxf(outv, 0.f), 1.f) * 2.f - 1.f;
        float lad = __logf(pk) + 1.09861228866810969f;   // + log(3)
        bool inside = (xin >= -1.f) && (xin <= 1.f);
        if (!inside) { outv = xin; lad = 0.f; }
        out[gpos] = outv;
        lad_acc += lad;
    }
#pragma unroll
    for (int off = 32; off > 0; off >>= 1)
        lad_acc += __shfl_down(lad_acc, off, 64);
    if (lane == 0) red[wid] = lad_acc;
    __syncthreads();
    if (t == 0) atomicAdd(out + 8388608 + b, red[0] + red[1] + red[2] + red[3]);
}

extern "C" void kernel_launch(void* const* d_in, const int* in_sizes, int n_in,
                              void* d_out, int out_size, void* d_ws, size_t ws_size,
                              hipStream_t stream) {
    const float* x   = (const float*)d_in[0];
    const float* obj = (const float*)d_in[1];
    const float* W1  = (const float*)d_in[2];
    const float* b1  = (const float*)d_in[3];
    const float* W2  = (const float*)d_in[4];
    const float* b2  = (const float*)d_in[5];
    float* out = (float*)d_out;
    char* ws = (char*)d_ws;

    unsigned short* x1b  = (unsigned short*)ws;                          //  8,388,608 B
    unsigned short* hbuf = (unsigned short*)(ws + 8388608);              // 33,554,432 B
    unsigned short* Wt1  = (unsigned short*)(ws + 8388608 + 33554432);   //     73,728 B
    unsigned short* Wt2  = (unsigned short*)(ws + 8388608 + 33554432 + 73728); // 221,184 B

    hipLaunchKernelGGL(prep_x1,      dim3(2048), dim3(256), 0, stream, x, x1b);
    hipLaunchKernelGGL(prep_copy,    dim3(4096), dim3(256), 0, stream, x, obj, out);
    hipLaunchKernelGGL(prep_w,       dim3(432),  dim3(256), 0, stream, W1, W2, Wt1, Wt2);
    hipLaunchKernelGGL(conv1_relu,   dim3(512),  dim3(256), 0, stream, x1b, b1, Wt1, hbuf);
    hipLaunchKernelGGL(conv2_spline, dim3(1024), dim3(256), 0, stream, hbuf, b2, Wt2, x, out);
}

// Round 3
// 105.922 us; speedup vs baseline: 1.0204x; 1.0204x over previous
//
#include <hip/hip_runtime.h>

typedef __attribute__((ext_vector_type(8))) __bf16 bf16x8;
typedef __attribute__((ext_vector_type(4))) float f32x4;

__device__ __forceinline__ unsigned short f2bf(float f) {
    unsigned int u = __builtin_bit_cast(unsigned int, f);
    u = (u + 0x7FFFu + ((u >> 16) & 1u)) >> 16;
    return (unsigned short)u;
}

// ---- K0a: transpose-cast identity half (ch 0..31) to channel-last bf16 ----
__global__ void __launch_bounds__(256) prep_x1(const float* __restrict__ x,
                                               unsigned short* __restrict__ x1b) {
    int bh = blockIdx.x;                  // b*64 + h
    __shared__ unsigned short lds[64][34];
    int t = threadIdx.x;
    int w = t & 63, c4 = t >> 6;
    const float* xp = x + (size_t)(bh >> 6) * 262144 + (size_t)(bh & 63) * 64;
#pragma unroll
    for (int co = 0; co < 8; ++co) {
        int c = co * 4 + c4;
        lds[w][c] = f2bf(xp[(size_t)c * 4096 + w]);
    }
    __syncthreads();
    int wq = t >> 2, c0 = (t & 3) * 8;
    uint4 v;
    unsigned short* pv = reinterpret_cast<unsigned short*>(&v);
#pragma unroll
    for (int j = 0; j < 8; ++j) pv[j] = lds[wq][c0 + j];
    *reinterpret_cast<uint4*>(x1b + ((size_t)bh * 64 + wq) * 32 + c0) = v;
}

// ---- K0b: copy identity half f32 -> out ch 0..31 ; init objective slots ----
__global__ void __launch_bounds__(256) prep_copy(const float* __restrict__ x,
                                                 const float* __restrict__ obj,
                                                 float* __restrict__ out) {
    unsigned tid = blockIdx.x * 256 + threadIdx.x;   // 1,048,576 float4 total
    unsigned b = tid >> 15, r = tid & 32767;
    size_t off = (size_t)b * 65536 + r;
    reinterpret_cast<float4*>(out)[off] = reinterpret_cast<const float4*>(x)[off];
    if (tid < 32) out[8388608 + tid] = obj[tid];
}

// ---- K0c: repack weights to [tap][o][i] bf16 ----
__global__ void __launch_bounds__(256) prep_w(const float* __restrict__ W1,
                                              const float* __restrict__ W2,
                                              unsigned short* __restrict__ Wt1,
                                              unsigned short* __restrict__ Wt2) {
    int tid = blockIdx.x * 256 + threadIdx.x;
    if (tid < 36864) {                       // W1: [128][32][9]
        int tt = tid % 9, rem = tid / 9;
        int i = rem & 31, o = rem >> 5;
        Wt1[(tt * 128 + o) * 32 + i] = f2bf(W1[tid]);
    }
    if (tid < 110592) {                      // W2: [96][128][9]
        int tt = tid % 9, rem = tid / 9;
        int i = rem & 127, o = rem >> 7;
        Wt2[(tt * 96 + o) * 128 + i] = f2bf(W2[tid]);
    }
}

// ---- K1: conv1 (32->128 ch) + bias + ReLU -> h bf16 channel-last ----
__global__ void __launch_bounds__(256) conv1_relu(const unsigned short* __restrict__ x1b,
                                                  const float* __restrict__ b1,
                                                  const unsigned short* __restrict__ Wt1,
                                                  unsigned short* __restrict__ hbuf) {
    const int LW = 40;                          // 32 ch + 8 pad (bank spread)
    __shared__ unsigned short sx[6 * 66 * LW];  // 31,680 B
    int wg = blockIdx.x;
    int b = wg >> 4, h0 = (wg & 15) << 2;       // TH = 4 rows
    int t = threadIdx.x;

    if (t < 48) {                               // zero halo cols 0 and 65
        int row = t >> 3, k = t & 7;
        int col = (k & 1) ? 65 : 0, c0 = (k >> 1) * 8;
        *reinterpret_cast<uint4*>(&sx[(row * 66 + col) * LW + c0]) = uint4{0, 0, 0, 0};
    }
#pragma unroll
    for (int j = 0; j < 6; ++j) {               // stage 6 rows x 64 w x 32 ch
        int idx = j * 256 + t;
        int row = idx >> 8, rem = idx & 255;
        int w = rem >> 2, c0 = (rem & 3) * 8;
        int gh = h0 - 1 + row;
        uint4 v = uint4{0, 0, 0, 0};
        if (gh >= 0 && gh < 64)
            v = *reinterpret_cast<const uint4*>(x1b + (((size_t)b * 64 + gh) * 64 + w) * 32 + c0);
        *reinterpret_cast<uint4*>(&sx[(row * 66 + (w + 1)) * LW + c0]) = v;
    }
    __syncthreads();

    int wid = t >> 6, lane = t & 63;
    int lrow = lane & 15, kgrp = lane >> 4;

    bf16x8 afr[2][9];                           // hoist weights: 2 M-tiles x 9 taps
#pragma unroll
    for (int m2 = 0; m2 < 2; ++m2) {
        int o = (wid * 2 + m2) * 16 + lrow;
#pragma unroll
        for (int tap = 0; tap < 9; ++tap)
            afr[m2][tap] = *reinterpret_cast<const bf16x8*>(
                Wt1 + (size_t)(tap * 128 + o) * 32 + kgrp * 8);
    }

    for (int nt = 0; nt < 16; ++nt) {
        int r = nt >> 2, ww = ((nt & 3) << 4) + lrow;
        f32x4 acc0 = {0.f, 0.f, 0.f, 0.f}, acc1 = {0.f, 0.f, 0.f, 0.f};
#pragma unroll
        for (int dh = 0; dh < 3; ++dh)
#pragma unroll
            for (int dw = 0; dw < 3; ++dw) {
                int tap = dh * 3 + dw;
                bf16x8 bfr = *reinterpret_cast<const bf16x8*>(
                    &sx[((r + dh) * 66 + ww + dw) * LW + kgrp * 8]);
                acc0 = __builtin_amdgcn_mfma_f32_16x16x32_bf16(afr[0][tap], bfr, acc0, 0, 0, 0);
                acc1 = __builtin_amdgcn_mfma_f32_16x16x32_bf16(afr[1][tap], bfr, acc1, 0, 0, 0);
            }
        int hh = h0 + r;
        size_t obase = (((size_t)b * 64 + hh) * 64 + ww) * 128;
#pragma unroll
        for (int m2 = 0; m2 < 2; ++m2) {
            f32x4 a = (m2 == 0) ? acc0 : acc1;
            int o0 = (wid * 2 + m2) * 16 + kgrp * 4;
            unsigned short r4[4];
#pragma unroll
            for (int j = 0; j < 4; ++j) {
                float v = a[j] + b1[o0 + j];
                r4[j] = f2bf(fmaxf(v, 0.f));
            }
            uint2 pk;
            pk.x = (unsigned)r4[0] | ((unsigned)r4[1] << 16);
            pk.y = (unsigned)r4[2] | ((unsigned)r4[3] << 16);
            *reinterpret_cast<uint2*>(hbuf + obase + o0) = pk;
        }
    }
}

// ---- K2: conv2 (128->96 ch) + bias -> params (LDS) -> spline -> out ----
// v2: full-K single stage (LW=136, conflict-free b128), register-double-buffered
//     tap-ahead weight prefetch, params stride 101 (odd -> conflict-free).
__global__ void __launch_bounds__(256) conv2_spline(const unsigned short* __restrict__ hbuf,
                                                    const float* __restrict__ b2,
                                                    const unsigned short* __restrict__ Wt2,
                                                    const float* __restrict__ x,
                                                    float* __restrict__ out) {
    const int LW = 136;                        // 128 ch + 8 pad: 272B row, slot stride 17
    __shared__ unsigned short sx[4 * 66 * LW]; // 71,808 B
    __shared__ float red[4];
    float* pm = reinterpret_cast<float*>(sx);  // params alias [128][101] f32 = 51,712 B
    int wg = blockIdx.x;
    int b = wg >> 5, h0 = (wg & 31) << 1;      // TH = 2 rows
    int t = threadIdx.x;
    int wid = t >> 6, lane = t & 63;
    int lrow = lane & 15, kgrp = lane >> 4;
    int ntb = (wid & 1) * 4;                   // wave's 4 N-tiles
    int mb = (wid >> 1) * 3;                   // wave's 3 M-tiles

    // ---- stage all 4 rows x 64 w x 128 ch in one pass ----
    if (t < 128) {                             // zero halo cols 0 and 65
        int row = t >> 5, k = t & 31;
        int col = (k & 1) ? 65 : 0, c0 = (k >> 1) * 8;
        *reinterpret_cast<uint4*>(&sx[(row * 66 + col) * LW + c0]) = uint4{0, 0, 0, 0};
    }
#pragma unroll
    for (int j = 0; j < 16; ++j) {             // 4096 uint4 chunks
        int idx = j * 256 + t;
        int row = idx >> 10, rem = idx & 1023;
        int w = rem >> 4, c0 = (rem & 15) * 8;
        int gh = h0 - 1 + row;
        uint4 v = uint4{0, 0, 0, 0};
        if (gh >= 0 && gh < 64)
            v = *reinterpret_cast<const uint4*>(
                hbuf + (((size_t)b * 64 + gh) * 64 + w) * 128 + c0);
        *reinterpret_cast<uint4*>(&sx[(row * 66 + (w + 1)) * LW + c0]) = v;
    }

    f32x4 acc[3][4];
#pragma unroll
    for (int i = 0; i < 3; ++i)
#pragma unroll
        for (int j = 0; j < 4; ++j) acc[i][j] = f32x4{0.f, 0.f, 0.f, 0.f};

    // weight fragment base for this lane (row o, k-slice kgrp)
    const unsigned short* wB = Wt2 + (size_t)(mb * 16 + lrow) * 128 + kgrp * 8;
    // double-buffered weight prefetch: wf[buf][mi][kc]
    bf16x8 wf[2][3][4];
#pragma unroll
    for (int mi = 0; mi < 3; ++mi)
#pragma unroll
        for (int kc = 0; kc < 4; ++kc)
            wf[0][mi][kc] = *reinterpret_cast<const bf16x8*>(
                wB + (size_t)mi * 16 * 128 + kc * 32);   // tap 0

    __syncthreads();

#pragma unroll
    for (int tap = 0; tap < 9; ++tap) {
        int cur = tap & 1;
        if (tap < 8) {                         // prefetch tap+1 weights (L2)
            const unsigned short* wp = wB + (size_t)(tap + 1) * 96 * 128;
#pragma unroll
            for (int mi = 0; mi < 3; ++mi)
#pragma unroll
                for (int kc = 0; kc < 4; ++kc)
                    wf[cur ^ 1][mi][kc] = *reinterpret_cast<const bf16x8*>(
                        wp + (size_t)mi * 16 * 128 + kc * 32);
        }
        int dh = tap / 3, dw = tap % 3;
#pragma unroll
        for (int ni = 0; ni < 4; ++ni) {
            int nt = ntb + ni;
            int rr = nt >> 2, ww = ((nt & 3) << 4) + lrow;
            int base = ((rr + dh) * 66 + ww + dw) * LW;
            bf16x8 bfr[4];
#pragma unroll
            for (int kc = 0; kc < 4; ++kc)
                bfr[kc] = *reinterpret_cast<const bf16x8*>(&sx[base + kc * 32 + kgrp * 8]);
#pragma unroll
            for (int mi = 0; mi < 3; ++mi)
#pragma unroll
                for (int kc = 0; kc < 4; ++kc)
                    acc[mi][ni] = __builtin_amdgcn_mfma_f32_16x16x32_bf16(
                        wf[cur][mi][kc], bfr[kc], acc[mi][ni], 0, 0, 0);
        }
    }
    __syncthreads();
    // params (+bias) -> LDS [p][101] (odd stride: conflict-free scalar access)
#pragma unroll
    for (int mi = 0; mi < 3; ++mi) {
        int o0 = (mb + mi) * 16 + kgrp * 4;
        float bb0 = b2[o0], bb1 = b2[o0 + 1], bb2 = b2[o0 + 2], bb3 = b2[o0 + 3];
#pragma unroll
        for (int ni = 0; ni < 4; ++ni) {
            int p = (ntb + ni) * 16 + lrow;
            f32x4 v = acc[mi][ni];
            pm[p * 101 + o0]     = v[0] + bb0;
            pm[p * 101 + o0 + 1] = v[1] + bb1;
            pm[p * 101 + o0 + 2] = v[2] + bb2;
            pm[p * 101 + o0 + 3] = v[3] + bb3;
        }
    }
    __syncthreads();

    // fused softmax + linear spline + identity tails + logabsdet
    float lad_acc = 0.f;
#pragma unroll 4
    for (int it = 0; it < 16; ++it) {
        int idx = it * 256 + t;
        int c = idx >> 7, p = idx & 127;
        float u0 = pm[p * 101 + 3 * c];
        float u1 = pm[p * 101 + 3 * c + 1];
        float u2 = pm[p * 101 + 3 * c + 2];
        size_t gpos = (size_t)(b * 64 + 32 + c) * 4096 + (size_t)(h0 + (p >> 6)) * 64 + (p & 63);
        float xin = x[gpos];
        float mx = fmaxf(u0, fmaxf(u1, u2));
        float e0 = __expf(u0 - mx), e1 = __expf(u1 - mx), e2 = __expf(u2 - mx);
        float s = e0 + e1 + e2;
        float inv = 1.0f / s;
        float pos = fminf(fmaxf((xin + 1.f) * 0.5f, 0.f), 1.f) * 3.f;
        int bin = (int)pos; bin = bin > 2 ? 2 : bin;
        float alpha = pos - (float)bin;
        float eb = (bin == 0) ? e0 : ((bin == 1) ? e1 : e2);
        float cb = (bin == 0) ? 0.f : ((bin == 1) ? e0 : (e0 + e1));
        float pk = eb * inv;
        float outv = cb * inv + alpha * pk;
        outv = fminf(fmaxf(outv, 0.f), 1.f) * 2.f - 1.f;
        float lad = __logf(pk) + 1.09861228866810969f;   // + log(3)
        bool inside = (xin >= -1.f) && (xin <= 1.f);
        if (!inside) { outv = xin; lad = 0.f; }
        out[gpos] = outv;
        lad_acc += lad;
    }
#pragma unroll
    for (int off = 32; off > 0; off >>= 1)
        lad_acc += __shfl_down(lad_acc, off, 64);
    if (lane == 0) red[wid] = lad_acc;
    __syncthreads();
    if (t == 0) atomicAdd(out + 8388608 + b, red[0] + red[1] + red[2] + red[3]);
}

extern "C" void kernel_launch(void* const* d_in, const int* in_sizes, int n_in,
                              void* d_out, int out_size, void* d_ws, size_t ws_size,
                              hipStream_t stream) {
    const float* x   = (const float*)d_in[0];
    const float* obj = (const float*)d_in[1];
    const float* W1  = (const float*)d_in[2];
    const float* b1  = (const float*)d_in[3];
    const float* W2  = (const float*)d_in[4];
    const float* b2  = (const float*)d_in[5];
    float* out = (float*)d_out;
    char* ws = (char*)d_ws;

    unsigned short* x1b  = (unsigned short*)ws;                          //  8,388,608 B
    unsigned short* hbuf = (unsigned short*)(ws + 8388608);              // 33,554,432 B
    unsigned short* Wt1  = (unsigned short*)(ws + 8388608 + 33554432);   //     73,728 B
    unsigned short* Wt2  = (unsigned short*)(ws + 8388608 + 33554432 + 73728); // 221,184 B

    hipLaunchKernelGGL(prep_x1,      dim3(2048), dim3(256), 0, stream, x, x1b);
    hipLaunchKernelGGL(prep_copy,    dim3(4096), dim3(256), 0, stream, x, obj, out);
    hipLaunchKernelGGL(prep_w,       dim3(432),  dim3(256), 0, stream, W1, W2, Wt1, Wt2);
    hipLaunchKernelGGL(conv1_relu,   dim3(512),  dim3(256), 0, stream, x1b, b1, Wt1, hbuf);
    hipLaunchKernelGGL(conv2_spline, dim3(1024), dim3(256), 0, stream, hbuf, b2, Wt2, x, out);
}